// Round 19
// baseline (123.836 us; speedup 1.0000x reference)
//
#include <hip/hip_runtime.h>
#include <stdint.h>

typedef unsigned short u16;
typedef __attribute__((ext_vector_type(8))) short short8;
typedef __attribute__((ext_vector_type(4))) float f32x4;
typedef __attribute__((ext_vector_type(16))) float f32x16;

__device__ __forceinline__ u16 f2bf(float f) {
  union { float f; unsigned int u; } c; c.f = f;
  return (u16)((c.u + 0x7FFFu + ((c.u >> 16) & 1u)) >> 16);
}

__device__ __forceinline__ float bf2f(u16 v) {
  union { unsigned int u; float f; } c; c.u = ((unsigned int)v) << 16;
  return c.f;
}

__device__ __forceinline__ f32x4 mfma16(short8 a, short8 b, f32x4 c) {
  return __builtin_amdgcn_mfma_f32_16x16x32_bf16(a, b, c, 0, 0, 0);
}

__device__ __forceinline__ f32x16 mfma32(short8 a, short8 b, f32x16 c) {
  return __builtin_amdgcn_mfma_f32_32x32x16_bf16(a, b, c, 0, 0, 0);
}

__device__ __forceinline__ void gl_lds16(const u16* g, u16* l) {
  __builtin_amdgcn_global_load_lds((const __attribute__((address_space(1))) void*)g,
                                   (__attribute__((address_space(3))) void*)l, 16, 0, 0);
}

// ---------------- fused cast f32 -> bf16 ----------------
__global__ __launch_bounds__(256) void cast_all(
    const float* __restrict__ x, const float* __restrict__ wq, const float* __restrict__ wk,
    const float* __restrict__ wv, const float* __restrict__ wo,
    u16* __restrict__ xb, u16* __restrict__ wqb, u16* __restrict__ wkb,
    u16* __restrict__ wvb, u16* __restrict__ wob) {
  int b = blockIdx.x;
  const float* src; u16* dst; int i;
  if (b < 4096)      { src = x;  dst = xb;  i = b * 256 + threadIdx.x; }
  else if (b < 5120) { src = wq; dst = wqb; i = (b - 4096) * 256 + threadIdx.x; }
  else if (b < 6144) { src = wk; dst = wkb; i = (b - 5120) * 256 + threadIdx.x; }
  else if (b < 7168) { src = wv; dst = wvb; i = (b - 6144) * 256 + threadIdx.x; }
  else               { src = wo; dst = wob; i = (b - 7168) * 256 + threadIdx.x; }
  float4 v = ((const float4*)src)[i];
  ushort4 o;
  o.x = f2bf(v.x); o.y = f2bf(v.y); o.z = f2bf(v.z); o.w = f2bf(v.w);
  ((ushort4*)dst)[i] = o;
}

// ---------------- fused QKV projection GEMM (BK=64, 2-phase, swizzled) ------
// Minimum 2-phase (T3-lite): double-buffered LDS; stage tile t+1 BEFORE
// computing tile t; raw s_barrier + manual vmcnt(0) at iteration END so the
// stage latency hides under ds_read+MFMA (no __syncthreads => no compiler
// pre-barrier full drain). T2 swizzle (R18, 0 conflicts): linear LDS dest,
// XOR-pre-swizzled global source, XOR-swizzled ds_read.
__global__ __launch_bounds__(256) void qkv_gemm(
    const u16* __restrict__ xb, const u16* __restrict__ wqb, const u16* __restrict__ wkb,
    const u16* __restrict__ wvb, const float* __restrict__ bq, const float* __restrict__ bk,
    const float* __restrict__ bv, u16* __restrict__ Qb, u16* __restrict__ Kb,
    u16* __restrict__ VTb) {
  __shared__ __align__(16) u16 As[2][128 * 64];
  __shared__ __align__(16) u16 Bs[2][128 * 64];
  const int id = blockIdx.x;
  const int s = id >> 3;
  const int mblk = (id & 7) + ((s & 3) << 3);
  const int z = (s >> 2) % 3;
  const int nblk = s / 12;
  const u16* __restrict__ W = (z == 0) ? wqb : (z == 1) ? wkb : wvb;
  const float* __restrict__ bias = (z == 0) ? bq : (z == 1) ? bk : bv;
  const int m0 = mblk * 128, n0 = nblk * 128;
  const int tid = threadIdx.x, lane = tid & 63, wave = tid >> 6;
  const int wr = (wave >> 1) * 64, wc = (wave & 1) * 64;
  const int fr = lane & 15, fg = lane >> 4;
  const int lrow = lane >> 3;
  const int lcol = (((lane & 7) ^ (lrow & 7)) * 8);  // pre-swizzled source chunk

  const u16* ga = xb + (size_t)(m0 + wave * 32 + lrow) * 1024 + lcol;
  const u16* gb = W  + (size_t)(n0 + wave * 32 + lrow) * 1024 + lcol;

  auto stage = [&](int k0, int b) {
    u16* la = As[b] + wave * 2048;
    u16* lb = Bs[b] + wave * 2048;
#pragma unroll
    for (int i = 0; i < 4; ++i) {
      gl_lds16(ga + k0 + (size_t)(8 * i) * 1024, la + i * 512);
      gl_lds16(gb + k0 + (size_t)(8 * i) * 1024, lb + i * 512);
    }
  };

  f32x4 acc[4][4] = {};

  stage(0, 0);
  asm volatile("s_waitcnt vmcnt(0)" ::: "memory");
  __builtin_amdgcn_s_barrier();
  __builtin_amdgcn_sched_barrier(0);

  for (int t = 0; t < 16; ++t) {
    const int cur = t & 1;
    if (t < 15) stage((t + 1) * 64, cur ^ 1);
    __builtin_amdgcn_sched_barrier(0);  // issue prefetch before compute
    const u16* Ac = As[cur];
    const u16* Bc = Bs[cur];
#pragma unroll
    for (int kk = 0; kk < 2; ++kk) {
      short8 a[4], b[4];
#pragma unroll
      for (int i = 0; i < 4; ++i)
        a[i] = *(const short8*)(Ac + (wr + i * 16 + fr) * 64 +
                                (((kk * 4 + fg) ^ (fr & 7)) * 8));
#pragma unroll
      for (int i = 0; i < 4; ++i)
        b[i] = *(const short8*)(Bc + (wc + i * 16 + fr) * 64 +
                                (((kk * 4 + fg) ^ (fr & 7)) * 8));
      __builtin_amdgcn_s_setprio(1);
#pragma unroll
      for (int i = 0; i < 4; ++i)
#pragma unroll
        for (int j = 0; j < 4; ++j) acc[i][j] = mfma16(a[i], b[j], acc[i][j]);
      __builtin_amdgcn_s_setprio(0);
    }
    // reads consumed by MFMAs (compiler lgkmcnt); drain prefetch, then barrier
    asm volatile("s_waitcnt vmcnt(0)" ::: "memory");
    __builtin_amdgcn_s_barrier();
    __builtin_amdgcn_sched_barrier(0);
  }

  const float qsc = (z == 0) ? (0.125f * 1.44269504088896f) : 1.0f;
#pragma unroll
  for (int j = 0; j < 4; ++j) {
    const int col = n0 + wc + j * 16 + fr;
    const float bcol = bias[col];
    const int h = col >> 6, d = col & 63;
#pragma unroll
    for (int i = 0; i < 4; ++i) {
#pragma unroll
      for (int r = 0; r < 4; ++r) {
        const int m = m0 + wr + i * 16 + fg * 4 + r;
        const int bi = m >> 11, t = m & 2047;
        const u16 o = f2bf((acc[i][j][r] + bcol) * qsc);
        const size_t bse = (size_t)(bi * 16 + h) << 17;
        if (z == 0)      Qb[bse + (size_t)t * 64 + d] = o;
        else if (z == 1) Kb[bse + (size_t)t * 64 + d] = o;
        else             VTb[bse + (size_t)d * 2048 + t] = o;
      }
    }
  }
}

// ---------------- flash causal attention (coalesced LDS-staged K/V) ----------
// (byte-identical to R15)
__global__ __launch_bounds__(256, 2) void attn_kernel(
    const u16* __restrict__ Qb, const u16* __restrict__ Kb, const u16* __restrict__ VTb,
    u16* __restrict__ aOb) {
  __shared__ __align__(16) char smem[49152];  // 4 waves x (K0 4K | K1 4K | V 4K); epilogue Ow aliases
  __shared__ float Mll[4][2][64];             // l partials, 2 KB
  u16* Ow = (u16*)smem;
  const int id = blockIdx.x;
  const int xcd = id & 7, wbl = id >> 3;
  const int cu = wbl & 31, rr = wbl >> 5;
  const int g = cu >> 2;
  const int bh = xcd + ((cu & 3) << 3);
  const int j = (rr == 0) ? 31 - g : (rr == 1) ? 16 + g : (rr == 2) ? 15 - g : g;
  const int tid = threadIdx.x, lane = tid & 63, wave = tid >> 6;
  const int l31 = lane & 31, hi = lane >> 5;
  const size_t base = (size_t)bh << 17;
  const int bi = bh >> 4, h = bh & 15;
  const int q0 = j * 64;

  u16* kb0 = (u16*)(smem + wave * 12288);
  u16* kb1 = (u16*)(smem + wave * 12288 + 4096);
  u16* vb  = (u16*)(smem + wave * 12288 + 8192);

  short8 qf[2][4];
  {
    const u16* qp = Qb + base + (size_t)(q0 + l31) * 64 + hi * 8;
#pragma unroll
    for (int mi = 0; mi < 2; ++mi)
#pragma unroll
      for (int st = 0; st < 4; ++st)
        qf[mi][st] = *(const short8*)(qp + mi * 32 * 64 + st * 16);
  }

  f32x16 oacc[2][2] = {};
  float lrun[2] = {0.f, 0.f};

  auto stageK = [&](int t0, u16* kb) {
    const u16* kp = Kb + base + (size_t)(t0 + (lane >> 3)) * 64 +
                    (((lane & 7) ^ ((lane >> 3) & 7)) * 8);
#pragma unroll
    for (int i = 0; i < 4; ++i) gl_lds16(kp + (size_t)(8 * i) * 64, kb + i * 512);
  };
  auto stageV = [&](int t0) {
    const u16* vp = VTb + base + (size_t)(lane >> 2) * 2048 + t0 +
                    (((lane & 3) ^ ((lane >> 2) & 3)) * 8);
#pragma unroll
    for (int i = 0; i < 4; ++i) gl_lds16(vp + (size_t)(16 * i) * 2048, vb + i * 512);
  };

  const int tmax = 2 * j + 1;  // KV units of 32 tokens
  if (wave <= tmax) {
    int buf = 0;
    stageK(wave * 32, kb0);
    stageV(wave * 32);
    for (int tu = wave; tu <= tmax; tu += 4) {
      const int t0 = tu * 32;
      const bool more = (tu + 4 <= tmax);
      if (more) {
        stageK((tu + 4) * 32, buf ? kb0 : kb1);
        asm volatile("s_waitcnt vmcnt(4)" ::: "memory");
      } else {
        asm volatile("s_waitcnt vmcnt(0)" ::: "memory");
      }
      __builtin_amdgcn_sched_barrier(0);
      const char* kb = (const char*)(buf ? kb1 : kb0);

      short8 kf[4];
#pragma unroll
      for (int st = 0; st < 4; ++st)
        kf[st] = *(const short8*)(kb + l31 * 128 + (((st * 2 + hi) ^ (l31 & 7)) << 4));
      short8 vf[2][2];
#pragma unroll
      for (int nb = 0; nb < 2; ++nb)
#pragma unroll
        for (int ks = 0; ks < 2; ++ks)
          vf[nb][ks] = *(const short8*)((const char*)vb + (nb * 32 + l31) * 64 +
                                        (((ks * 2 + hi) ^ (l31 & 3)) << 4));

#pragma unroll
      for (int mi = 0; mi < 2; ++mi) {
        f32x16 s = {};
        __builtin_amdgcn_s_setprio(1);
        s = mfma32(kf[0], qf[mi][0], s);
        s = mfma32(kf[1], qf[mi][1], s);
        s = mfma32(kf[2], qf[mi][2], s);
        s = mfma32(kf[3], qf[mi][3], s);
        __builtin_amdgcn_s_setprio(0);

        if (t0 + 31 > q0 + mi * 32) {
          const int qv = q0 + mi * 32 + l31;
#pragma unroll
          for (int r = 0; r < 16; ++r) {
            const int tl = t0 + (r & 3) + ((r >> 2) << 3) + hi * 4;
            if (tl > qv) s[r] = -1e30f;
          }
        }

        float rs = 0.f;
#pragma unroll
        for (int r = 0; r < 16; ++r) {
          const float pv = exp2f(s[r]);
          s[r] = pv;
          rs += pv;
        }
        lrun[mi] += rs;

        uint32_t w0, w1, w2, w3, w4, w5, w6, w7;
        asm("v_cvt_pk_bf16_f32 %0, %1, %2" : "=v"(w0) : "v"(s[0]),  "v"(s[1]));
        asm("v_cvt_pk_bf16_f32 %0, %1, %2" : "=v"(w1) : "v"(s[2]),  "v"(s[3]));
        asm("v_cvt_pk_bf16_f32 %0, %1, %2" : "=v"(w2) : "v"(s[4]),  "v"(s[5]));
        asm("v_cvt_pk_bf16_f32 %0, %1, %2" : "=v"(w3) : "v"(s[6]),  "v"(s[7]));
        asm("v_cvt_pk_bf16_f32 %0, %1, %2" : "=v"(w4) : "v"(s[8]),  "v"(s[9]));
        asm("v_cvt_pk_bf16_f32 %0, %1, %2" : "=v"(w5) : "v"(s[10]), "v"(s[11]));
        asm("v_cvt_pk_bf16_f32 %0, %1, %2" : "=v"(w6) : "v"(s[12]), "v"(s[13]));
        asm("v_cvt_pk_bf16_f32 %0, %1, %2" : "=v"(w7) : "v"(s[14]), "v"(s[15]));
        asm("v_permlane32_swap_b32 %0, %1" : "+v"(w0), "+v"(w2));
        asm("v_permlane32_swap_b32 %0, %1" : "+v"(w1), "+v"(w3));
        asm("v_permlane32_swap_b32 %0, %1" : "+v"(w4), "+v"(w6));
        asm("v_permlane32_swap_b32 %0, %1" : "+v"(w5), "+v"(w7));
        short8 pa0, pa1;
        {
          uint32_t* p0 = (uint32_t*)&pa0;
          p0[0] = w0; p0[1] = w1; p0[2] = w2; p0[3] = w3;
          uint32_t* p1 = (uint32_t*)&pa1;
          p1[0] = w4; p1[1] = w5; p1[2] = w6; p1[3] = w7;
        }

        __builtin_amdgcn_s_setprio(1);
        oacc[mi][0] = mfma32(pa0, vf[0][0], oacc[mi][0]);
        oacc[mi][0] = mfma32(pa1, vf[0][1], oacc[mi][0]);
        oacc[mi][1] = mfma32(pa0, vf[1][0], oacc[mi][1]);
        oacc[mi][1] = mfma32(pa1, vf[1][1], oacc[mi][1]);
        __builtin_amdgcn_s_setprio(0);
      }

      if (more) {
        asm volatile("s_waitcnt lgkmcnt(0)" ::: "memory");
        __builtin_amdgcn_sched_barrier(0);
        stageV((tu + 4) * 32);
      }
      buf ^= 1;
    }
  }

  __syncthreads();  // staging LDS dead; Ow takes over the aliased space
#pragma unroll
  for (int mi = 0; mi < 2; ++mi) Mll[wave][hi][mi * 32 + l31] = lrun[mi];
#pragma unroll
  for (int mi = 0; mi < 2; ++mi)
#pragma unroll
    for (int nb = 0; nb < 2; ++nb)
#pragma unroll
      for (int r = 0; r < 16; ++r) {
        const int q = mi * 32 + (r & 3) + ((r >> 2) << 3) + hi * 4;
        Ow[(wave * 64 + q) * 72 + nb * 32 + l31] = f2bf(oacc[mi][nb][r]);
      }
  __syncthreads();

  const int rq = tid >> 2, c0 = (tid & 3) * 16;
  float lt = 0.f;
#pragma unroll
  for (int w = 0; w < 4; ++w)
#pragma unroll
    for (int gg = 0; gg < 2; ++gg) lt += Mll[w][gg][rq];
  const float inv = __builtin_amdgcn_rcpf(lt);
  float o[16] = {};
#pragma unroll
  for (int w = 0; w < 4; ++w) {
    const u16* orow = &Ow[(w * 64 + rq) * 72 + c0];
    short8 a = *(const short8*)orow;
    short8 b = *(const short8*)(orow + 8);
#pragma unroll
    for (int i = 0; i < 8; ++i) {
      o[i]     += bf2f((u16)a[i]);
      o[8 + i] += bf2f((u16)b[i]);
    }
  }
  short8 r0, r1;
#pragma unroll
  for (int i = 0; i < 8; ++i) {
    r0[i] = (short)f2bf(o[i] * inv);
    r1[i] = (short)f2bf(o[8 + i] * inv);
  }
  u16* op = aOb + ((size_t)bi * 2048 + q0 + rq) * 1024 + h * 64 + c0;
  *(short8*)op = r0;
  *(short8*)(op + 8) = r1;
}

// ---------------- output projection GEMM (BK=64, 2-phase, swizzled) ----------
__global__ __launch_bounds__(256) void out_gemm(
    const u16* __restrict__ Ab, const u16* __restrict__ Wb, const float* __restrict__ bo,
    float* __restrict__ out) {
  __shared__ __align__(16) u16 As[2][128 * 64];
  __shared__ __align__(16) u16 Bs[2][128 * 64];
  const int id = blockIdx.x;
  const int s = id >> 3;
  const int m0 = ((id & 7) + ((s & 3) << 3)) * 128;
  const int n0 = (s >> 2) * 128;
  const int tid = threadIdx.x, lane = tid & 63, wave = tid >> 6;
  const int wr = (wave >> 1) * 64, wc = (wave & 1) * 64;
  const int fr = lane & 15, fg = lane >> 4;
  const int lrow = lane >> 3;
  const int lcol = (((lane & 7) ^ (lrow & 7)) * 8);

  const u16* ga = Ab + (size_t)(m0 + wave * 32 + lrow) * 1024 + lcol;
  const u16* gb = Wb + (size_t)(n0 + wave * 32 + lrow) * 1024 + lcol;

  auto stage = [&](int k0, int b) {
    u16* la = As[b] + wave * 2048;
    u16* lb = Bs[b] + wave * 2048;
#pragma unroll
    for (int i = 0; i < 4; ++i) {
      gl_lds16(ga + k0 + (size_t)(8 * i) * 1024, la + i * 512);
      gl_lds16(gb + k0 + (size_t)(8 * i) * 1024, lb + i * 512);
    }
  };

  f32x4 acc[4][4] = {};

  stage(0, 0);
  asm volatile("s_waitcnt vmcnt(0)" ::: "memory");
  __builtin_amdgcn_s_barrier();
  __builtin_amdgcn_sched_barrier(0);

  for (int t = 0; t < 16; ++t) {
    const int cur = t & 1;
    if (t < 15) stage((t + 1) * 64, cur ^ 1);
    __builtin_amdgcn_sched_barrier(0);
    const u16* Ac = As[cur];
    const u16* Bc = Bs[cur];
#pragma unroll
    for (int kk = 0; kk < 2; ++kk) {
      short8 a[4], b[4];
#pragma unroll
      for (int i = 0; i < 4; ++i)
        a[i] = *(const short8*)(Ac + (wr + i * 16 + fr) * 64 +
                                (((kk * 4 + fg) ^ (fr & 7)) * 8));
#pragma unroll
      for (int i = 0; i < 4; ++i)
        b[i] = *(const short8*)(Bc + (wc + i * 16 + fr) * 64 +
                                (((kk * 4 + fg) ^ (fr & 7)) * 8));
      __builtin_amdgcn_s_setprio(1);
#pragma unroll
      for (int i = 0; i < 4; ++i)
#pragma unroll
        for (int j = 0; j < 4; ++j) acc[i][j] = mfma16(a[i], b[j], acc[i][j]);
      __builtin_amdgcn_s_setprio(0);
    }
    asm volatile("s_waitcnt vmcnt(0)" ::: "memory");
    __builtin_amdgcn_s_barrier();
    __builtin_amdgcn_sched_barrier(0);
  }

#pragma unroll
  for (int j = 0; j < 4; ++j) {
    const int col = n0 + wc + j * 16 + fr;
    const float bcol = bo[col];
#pragma unroll
    for (int i = 0; i < 4; ++i)
#pragma unroll
      for (int r = 0; r < 4; ++r) {
        const int m = m0 + wr + i * 16 + fg * 4 + r;
        out[(size_t)m * 1024 + col] = acc[i][j][r] + bcol;
      }
  }
}

extern "C" void kernel_launch(void* const* d_in, const int* in_sizes, int n_in,
                              void* d_out, int out_size, void* d_ws, size_t ws_size,
                              hipStream_t stream) {
  (void)in_sizes; (void)n_in; (void)out_size; (void)ws_size;
  const float* x  = (const float*)d_in[0];
  const float* Wq = (const float*)d_in[1];
  const float* bq = (const float*)d_in[2];
  const float* Wk = (const float*)d_in[3];
  const float* bk = (const float*)d_in[4];
  const float* Wv = (const float*)d_in[5];
  const float* bv = (const float*)d_in[6];
  const float* Wo = (const float*)d_in[7];
  const float* bo = (const float*)d_in[8];
  float* out = (float*)d_out;
  char* ws = (char*)d_ws;

  const size_t MB = 1024 * 1024;
  u16* xb  = (u16*)(ws);
  u16* wqb = (u16*)(ws + 8 * MB);
  u16* wkb = (u16*)(ws + 10 * MB);
  u16* wvb = (u16*)(ws + 12 * MB);
  u16* wob = (u16*)(ws + 14 * MB);
  u16* Qb  = (u16*)(ws + 16 * MB);
  u16* Kb  = (u16*)(ws + 24 * MB);
  u16* VTb = (u16*)(ws + 32 * MB);
  u16* aOb = (u16*)(ws + 40 * MB);

  cast_all<<<8192, 256, 0, stream>>>(x, Wq, Wk, Wv, Wo, xb, wqb, wkb, wvb, wob);
  qkv_gemm<<<768, 256, 0, stream>>>(xb, wqb, wkb, wvb, bq, bk, bv, Qb, Kb, VTb);
  attn_kernel<<<1024, 256, 0, stream>>>(Qb, Kb, VTb, aOb);
  out_gemm<<<256, 256, 0, stream>>>(aOb, wob, bo, out);
}

// Round 20
// 113.090 us; speedup vs baseline: 1.0950x; 1.0950x over previous
//
#include <hip/hip_runtime.h>
#include <stdint.h>

typedef unsigned short u16;
typedef __attribute__((ext_vector_type(8))) short short8;
typedef __attribute__((ext_vector_type(4))) float f32x4;
typedef __attribute__((ext_vector_type(16))) float f32x16;

__device__ __forceinline__ u16 f2bf(float f) {
  union { float f; unsigned int u; } c; c.f = f;
  return (u16)((c.u + 0x7FFFu + ((c.u >> 16) & 1u)) >> 16);
}

__device__ __forceinline__ float bf2f(u16 v) {
  union { unsigned int u; float f; } c; c.u = ((unsigned int)v) << 16;
  return c.f;
}

__device__ __forceinline__ f32x4 mfma16(short8 a, short8 b, f32x4 c) {
  return __builtin_amdgcn_mfma_f32_16x16x32_bf16(a, b, c, 0, 0, 0);
}

__device__ __forceinline__ f32x16 mfma32(short8 a, short8 b, f32x16 c) {
  return __builtin_amdgcn_mfma_f32_32x32x16_bf16(a, b, c, 0, 0, 0);
}

__device__ __forceinline__ void gl_lds16(const u16* g, u16* l) {
  __builtin_amdgcn_global_load_lds((const __attribute__((address_space(1))) void*)g,
                                   (__attribute__((address_space(3))) void*)l, 16, 0, 0);
}

// ---------------- fused cast f32 -> bf16 ----------------
__global__ __launch_bounds__(256) void cast_all(
    const float* __restrict__ x, const float* __restrict__ wq, const float* __restrict__ wk,
    const float* __restrict__ wv, const float* __restrict__ wo,
    u16* __restrict__ xb, u16* __restrict__ wqb, u16* __restrict__ wkb,
    u16* __restrict__ wvb, u16* __restrict__ wob) {
  int b = blockIdx.x;
  const float* src; u16* dst; int i;
  if (b < 4096)      { src = x;  dst = xb;  i = b * 256 + threadIdx.x; }
  else if (b < 5120) { src = wq; dst = wqb; i = (b - 4096) * 256 + threadIdx.x; }
  else if (b < 6144) { src = wk; dst = wkb; i = (b - 5120) * 256 + threadIdx.x; }
  else if (b < 7168) { src = wv; dst = wvb; i = (b - 6144) * 256 + threadIdx.x; }
  else               { src = wo; dst = wob; i = (b - 7168) * 256 + threadIdx.x; }
  float4 v = ((const float4*)src)[i];
  ushort4 o;
  o.x = f2bf(v.x); o.y = f2bf(v.y); o.z = f2bf(v.z); o.w = f2bf(v.w);
  ((ushort4*)dst)[i] = o;
}

// ---------------- fused QKV projection GEMM (co-resident z-sharing) ---------
// id in [0,768): z = id>>8, u = id&255, xcd = u&7, mgrp = (u>>3)&3, nblk = u>>5.
// CU slot hosts ids {u, u+256, u+512} -> SAME (mblk, nblk), z = 0,1,2: the
// A-tile (x-panel) addresses are identical across the co-resident triple
// (L1-hot) and B-slices are 3 z-variants of one panel (was: 3 unrelated
// panels + 3 m-groups per CU). BK=32, R15 staging + direct-store epilogue.
__global__ __launch_bounds__(256) void qkv_gemm(
    const u16* __restrict__ xb, const u16* __restrict__ wqb, const u16* __restrict__ wkb,
    const u16* __restrict__ wvb, const float* __restrict__ bq, const float* __restrict__ bk,
    const float* __restrict__ bv, u16* __restrict__ Qb, u16* __restrict__ Kb,
    u16* __restrict__ VTb) {
  __shared__ __align__(16) u16 As[128 * 32];
  __shared__ __align__(16) u16 Bs[128 * 32];
  const int id = blockIdx.x;
  const int z = id >> 8;
  const int u = id & 255;
  const int mblk = (u & 7) + (((u >> 3) & 3) << 3);
  const int nblk = u >> 5;
  const u16* __restrict__ W = (z == 0) ? wqb : (z == 1) ? wkb : wvb;
  const float* __restrict__ bias = (z == 0) ? bq : (z == 1) ? bk : bv;
  const int m0 = mblk * 128, n0 = nblk * 128;
  const int tid = threadIdx.x, lane = tid & 63, wave = tid >> 6;
  const int wr = (wave >> 1) * 64, wc = (wave & 1) * 64;
  const int fr = lane & 15, fg = lane >> 4;
  const int lrow = lane >> 2, lcol = (lane & 3) * 8;

  const u16* ga = xb + (size_t)(m0 + wave * 16 + lrow) * 1024 + lcol;
  const u16* gb = W  + (size_t)(n0 + wave * 16 + lrow) * 1024 + lcol;
  u16* la = As + wave * 512;
  u16* lb = Bs + wave * 512;

  f32x4 acc[4][4] = {};

  for (int k0 = 0; k0 < 1024; k0 += 32) {
    gl_lds16(ga + k0, la);
    gl_lds16(ga + 64 * 1024 + k0, la + 2048);
    gl_lds16(gb + k0, lb);
    gl_lds16(gb + 64 * 1024 + k0, lb + 2048);
    __syncthreads();
    short8 a[4], b[4];
#pragma unroll
    for (int i = 0; i < 4; ++i) a[i] = *(const short8*)(As + (wr + i * 16 + fr) * 32 + fg * 8);
#pragma unroll
    for (int i = 0; i < 4; ++i) b[i] = *(const short8*)(Bs + (wc + i * 16 + fr) * 32 + fg * 8);
#pragma unroll
    for (int i = 0; i < 4; ++i)
#pragma unroll
      for (int j = 0; j < 4; ++j) acc[i][j] = mfma16(a[i], b[j], acc[i][j]);
    __syncthreads();
  }

  const float qsc = (z == 0) ? (0.125f * 1.44269504088896f) : 1.0f;
#pragma unroll
  for (int j = 0; j < 4; ++j) {
    const int col = n0 + wc + j * 16 + fr;
    const float bcol = bias[col];
    const int h = col >> 6, d = col & 63;
#pragma unroll
    for (int i = 0; i < 4; ++i) {
#pragma unroll
      for (int r = 0; r < 4; ++r) {
        const int m = m0 + wr + i * 16 + fg * 4 + r;
        const int bi = m >> 11, t = m & 2047;
        const u16 o = f2bf((acc[i][j][r] + bcol) * qsc);
        const size_t bse = (size_t)(bi * 16 + h) << 17;
        if (z == 0)      Qb[bse + (size_t)t * 64 + d] = o;
        else if (z == 1) Kb[bse + (size_t)t * 64 + d] = o;
        else             VTb[bse + (size_t)d * 2048 + t] = o;
      }
    }
  }
}

// ---------------- flash causal attention (coalesced LDS-staged K/V) ----------
// (byte-identical to R15: best-measured 45.3 us)
__global__ __launch_bounds__(256, 2) void attn_kernel(
    const u16* __restrict__ Qb, const u16* __restrict__ Kb, const u16* __restrict__ VTb,
    u16* __restrict__ aOb) {
  __shared__ __align__(16) char smem[49152];  // 4 waves x (K0 4K | K1 4K | V 4K); epilogue Ow aliases
  __shared__ float Mll[4][2][64];             // l partials, 2 KB
  u16* Ow = (u16*)smem;
  const int id = blockIdx.x;
  const int xcd = id & 7, wbl = id >> 3;
  const int cu = wbl & 31, rr = wbl >> 5;
  const int g = cu >> 2;
  const int bh = xcd + ((cu & 3) << 3);
  const int j = (rr == 0) ? 31 - g : (rr == 1) ? 16 + g : (rr == 2) ? 15 - g : g;
  const int tid = threadIdx.x, lane = tid & 63, wave = tid >> 6;
  const int l31 = lane & 31, hi = lane >> 5;
  const size_t base = (size_t)bh << 17;
  const int bi = bh >> 4, h = bh & 15;
  const int q0 = j * 64;

  u16* kb0 = (u16*)(smem + wave * 12288);
  u16* kb1 = (u16*)(smem + wave * 12288 + 4096);
  u16* vb  = (u16*)(smem + wave * 12288 + 8192);

  short8 qf[2][4];
  {
    const u16* qp = Qb + base + (size_t)(q0 + l31) * 64 + hi * 8;
#pragma unroll
    for (int mi = 0; mi < 2; ++mi)
#pragma unroll
      for (int st = 0; st < 4; ++st)
        qf[mi][st] = *(const short8*)(qp + mi * 32 * 64 + st * 16);
  }

  f32x16 oacc[2][2] = {};
  float lrun[2] = {0.f, 0.f};

  auto stageK = [&](int t0, u16* kb) {
    const u16* kp = Kb + base + (size_t)(t0 + (lane >> 3)) * 64 +
                    (((lane & 7) ^ ((lane >> 3) & 7)) * 8);
#pragma unroll
    for (int i = 0; i < 4; ++i) gl_lds16(kp + (size_t)(8 * i) * 64, kb + i * 512);
  };
  auto stageV = [&](int t0) {
    const u16* vp = VTb + base + (size_t)(lane >> 2) * 2048 + t0 +
                    (((lane & 3) ^ ((lane >> 2) & 3)) * 8);
#pragma unroll
    for (int i = 0; i < 4; ++i) gl_lds16(vp + (size_t)(16 * i) * 2048, vb + i * 512);
  };

  const int tmax = 2 * j + 1;  // KV units of 32 tokens
  if (wave <= tmax) {
    int buf = 0;
    stageK(wave * 32, kb0);
    stageV(wave * 32);
    for (int tu = wave; tu <= tmax; tu += 4) {
      const int t0 = tu * 32;
      const bool more = (tu + 4 <= tmax);
      if (more) {
        stageK((tu + 4) * 32, buf ? kb0 : kb1);
        asm volatile("s_waitcnt vmcnt(4)" ::: "memory");
      } else {
        asm volatile("s_waitcnt vmcnt(0)" ::: "memory");
      }
      __builtin_amdgcn_sched_barrier(0);
      const char* kb = (const char*)(buf ? kb1 : kb0);

      short8 kf[4];
#pragma unroll
      for (int st = 0; st < 4; ++st)
        kf[st] = *(const short8*)(kb + l31 * 128 + (((st * 2 + hi) ^ (l31 & 7)) << 4));
      short8 vf[2][2];
#pragma unroll
      for (int nb = 0; nb < 2; ++nb)
#pragma unroll
        for (int ks = 0; ks < 2; ++ks)
          vf[nb][ks] = *(const short8*)((const char*)vb + (nb * 32 + l31) * 64 +
                                        (((ks * 2 + hi) ^ (l31 & 3)) << 4));

#pragma unroll
      for (int mi = 0; mi < 2; ++mi) {
        f32x16 s = {};
        __builtin_amdgcn_s_setprio(1);
        s = mfma32(kf[0], qf[mi][0], s);
        s = mfma32(kf[1], qf[mi][1], s);
        s = mfma32(kf[2], qf[mi][2], s);
        s = mfma32(kf[3], qf[mi][3], s);
        __builtin_amdgcn_s_setprio(0);

        if (t0 + 31 > q0 + mi * 32) {
          const int qv = q0 + mi * 32 + l31;
#pragma unroll
          for (int r = 0; r < 16; ++r) {
            const int tl = t0 + (r & 3) + ((r >> 2) << 3) + hi * 4;
            if (tl > qv) s[r] = -1e30f;
          }
        }

        float rs = 0.f;
#pragma unroll
        for (int r = 0; r < 16; ++r) {
          const float pv = exp2f(s[r]);
          s[r] = pv;
          rs += pv;
        }
        lrun[mi] += rs;

        uint32_t w0, w1, w2, w3, w4, w5, w6, w7;
        asm("v_cvt_pk_bf16_f32 %0, %1, %2" : "=v"(w0) : "v"(s[0]),  "v"(s[1]));
        asm("v_cvt_pk_bf16_f32 %0, %1, %2" : "=v"(w1) : "v"(s[2]),  "v"(s[3]));
        asm("v_cvt_pk_bf16_f32 %0, %1, %2" : "=v"(w2) : "v"(s[4]),  "v"(s[5]));
        asm("v_cvt_pk_bf16_f32 %0, %1, %2" : "=v"(w3) : "v"(s[6]),  "v"(s[7]));
        asm("v_cvt_pk_bf16_f32 %0, %1, %2" : "=v"(w4) : "v"(s[8]),  "v"(s[9]));
        asm("v_cvt_pk_bf16_f32 %0, %1, %2" : "=v"(w5) : "v"(s[10]), "v"(s[11]));
        asm("v_cvt_pk_bf16_f32 %0, %1, %2" : "=v"(w6) : "v"(s[12]), "v"(s[13]));
        asm("v_cvt_pk_bf16_f32 %0, %1, %2" : "=v"(w7) : "v"(s[14]), "v"(s[15]));
        asm("v_permlane32_swap_b32 %0, %1" : "+v"(w0), "+v"(w2));
        asm("v_permlane32_swap_b32 %0, %1" : "+v"(w1), "+v"(w3));
        asm("v_permlane32_swap_b32 %0, %1" : "+v"(w4), "+v"(w6));
        asm("v_permlane32_swap_b32 %0, %1" : "+v"(w5), "+v"(w7));
        short8 pa0, pa1;
        {
          uint32_t* p0 = (uint32_t*)&pa0;
          p0[0] = w0; p0[1] = w1; p0[2] = w2; p0[3] = w3;
          uint32_t* p1 = (uint32_t*)&pa1;
          p1[0] = w4; p1[1] = w5; p1[2] = w6; p1[3] = w7;
        }

        __builtin_amdgcn_s_setprio(1);
        oacc[mi][0] = mfma32(pa0, vf[0][0], oacc[mi][0]);
        oacc[mi][0] = mfma32(pa1, vf[0][1], oacc[mi][0]);
        oacc[mi][1] = mfma32(pa0, vf[1][0], oacc[mi][1]);
        oacc[mi][1] = mfma32(pa1, vf[1][1], oacc[mi][1]);
        __builtin_amdgcn_s_setprio(0);
      }

      if (more) {
        asm volatile("s_waitcnt lgkmcnt(0)" ::: "memory");
        __builtin_amdgcn_sched_barrier(0);
        stageV((tu + 4) * 32);
      }
      buf ^= 1;
    }
  }

  __syncthreads();  // staging LDS dead; Ow takes over the aliased space
#pragma unroll
  for (int mi = 0; mi < 2; ++mi) Mll[wave][hi][mi * 32 + l31] = lrun[mi];
#pragma unroll
  for (int mi = 0; mi < 2; ++mi)
#pragma unroll
    for (int nb = 0; nb < 2; ++nb)
#pragma unroll
      for (int r = 0; r < 16; ++r) {
        const int q = mi * 32 + (r & 3) + ((r >> 2) << 3) + hi * 4;
        Ow[(wave * 64 + q) * 72 + nb * 32 + l31] = f2bf(oacc[mi][nb][r]);
      }
  __syncthreads();

  const int rq = tid >> 2, c0 = (tid & 3) * 16;
  float lt = 0.f;
#pragma unroll
  for (int w = 0; w < 4; ++w)
#pragma unroll
    for (int gg = 0; gg < 2; ++gg) lt += Mll[w][gg][rq];
  const float inv = __builtin_amdgcn_rcpf(lt);
  float o[16] = {};
#pragma unroll
  for (int w = 0; w < 4; ++w) {
    const u16* orow = &Ow[(w * 64 + rq) * 72 + c0];
    short8 a = *(const short8*)orow;
    short8 b = *(const short8*)(orow + 8);
#pragma unroll
    for (int i = 0; i < 8; ++i) {
      o[i]     += bf2f((u16)a[i]);
      o[8 + i] += bf2f((u16)b[i]);
    }
  }
  short8 r0, r1;
#pragma unroll
  for (int i = 0; i < 8; ++i) {
    r0[i] = (short)f2bf(o[i] * inv);
    r1[i] = (short)f2bf(o[8 + i] * inv);
  }
  u16* op = aOb + ((size_t)bi * 2048 + q0 + rq) * 1024 + h * 64 + c0;
  *(short8*)op = r0;
  *(short8*)(op + 8) = r1;
}

// ---------------- output projection GEMM (R15 exact) -------------------------
__global__ __launch_bounds__(256) void out_gemm(
    const u16* __restrict__ Ab, const u16* __restrict__ Wb, const float* __restrict__ bo,
    float* __restrict__ out) {
  __shared__ __align__(16) u16 As[128 * 32];
  __shared__ __align__(16) u16 Bs[128 * 32];
  const int id = blockIdx.x;
  const int s = id >> 3;
  const int m0 = ((id & 7) + ((s & 3) << 3)) * 128;
  const int n0 = (s >> 2) * 128;
  const int tid = threadIdx.x, lane = tid & 63, wave = tid >> 6;
  const int wr = (wave >> 1) * 64, wc = (wave & 1) * 64;
  const int fr = lane & 15, fg = lane >> 4;
  const int lrow = lane >> 2, lcol = (lane & 3) * 8;

  const u16* ga = Ab + (size_t)(m0 + wave * 16 + lrow) * 1024 + lcol;
  const u16* gb = Wb + (size_t)(n0 + wave * 16 + lrow) * 1024 + lcol;
  u16* la = As + wave * 512;
  u16* lb = Bs + wave * 512;

  f32x4 acc[4][4] = {};

  for (int k0 = 0; k0 < 1024; k0 += 32) {
    gl_lds16(ga + k0, la);
    gl_lds16(ga + 64 * 1024 + k0, la + 2048);
    gl_lds16(gb + k0, lb);
    gl_lds16(gb + 64 * 1024 + k0, lb + 2048);
    __syncthreads();
    short8 a[4], b[4];
#pragma unroll
    for (int i = 0; i < 4; ++i) a[i] = *(const short8*)(As + (wr + i * 16 + fr) * 32 + fg * 8);
#pragma unroll
    for (int i = 0; i < 4; ++i) b[i] = *(const short8*)(Bs + (wc + i * 16 + fr) * 32 + fg * 8);
#pragma unroll
    for (int i = 0; i < 4; ++i)
#pragma unroll
      for (int j = 0; j < 4; ++j) acc[i][j] = mfma16(a[i], b[j], acc[i][j]);
    __syncthreads();
  }

#pragma unroll
  for (int j = 0; j < 4; ++j) {
    const int col = n0 + wc + j * 16 + fr;
    const float bcol = bo[col];
#pragma unroll
    for (int i = 0; i < 4; ++i)
#pragma unroll
      for (int r = 0; r < 4; ++r) {
        const int m = m0 + wr + i * 16 + fg * 4 + r;
        out[(size_t)m * 1024 + col] = acc[i][j][r] + bcol;
      }
  }
}

extern "C" void kernel_launch(void* const* d_in, const int* in_sizes, int n_in,
                              void* d_out, int out_size, void* d_ws, size_t ws_size,
                              hipStream_t stream) {
  (void)in_sizes; (void)n_in; (void)out_size; (void)ws_size;
  const float* x  = (const float*)d_in[0];
  const float* Wq = (const float*)d_in[1];
  const float* bq = (const float*)d_in[2];
  const float* Wk = (const float*)d_in[3];
  const float* bk = (const float*)d_in[4];
  const float* Wv = (const float*)d_in[5];
  const float* bv = (const float*)d_in[6];
  const float* Wo = (const float*)d_in[7];
  const float* bo = (const float*)d_in[8];
  float* out = (float*)d_out;
  char* ws = (char*)d_ws;

  const size_t MB = 1024 * 1024;
  u16* xb  = (u16*)(ws);
  u16* wqb = (u16*)(ws + 8 * MB);
  u16* wkb = (u16*)(ws + 10 * MB);
  u16* wvb = (u16*)(ws + 12 * MB);
  u16* wob = (u16*)(ws + 14 * MB);
  u16* Qb  = (u16*)(ws + 16 * MB);
  u16* Kb  = (u16*)(ws + 24 * MB);
  u16* VTb = (u16*)(ws + 32 * MB);
  u16* aOb = (u16*)(ws + 40 * MB);

  cast_all<<<8192, 256, 0, stream>>>(x, Wq, Wk, Wv, Wo, xb, wqb, wkb, wvb, wob);
  qkv_gemm<<<768, 256, 0, stream>>>(xb, wqb, wkb, wvb, bq, bk, bv, Qb, Kb, VTb);
  attn_kernel<<<1024, 256, 0, stream>>>(Qb, Kb, VTb, aOb);
  out_gemm<<<256, 256, 0, stream>>>(aOb, wob, bo, out);
}